// Round 5
// baseline (343.527 us; speedup 1.0000x reference)
//
#include <hip/hip_runtime.h>
#include <hip/hip_bf16.h>
#include <math.h>

#define HW   4096
#define CCH  256
#define NE   8
#define HID  512
#define NTOK 65536
#define PADH 260   // Hs row pitch (elems): +4 pad -> conflict-free writes, 4-way reads

typedef short s16x8 __attribute__((ext_vector_type(8)));
typedef float f32x4 __attribute__((ext_vector_type(4)));
typedef unsigned short u16x8 __attribute__((ext_vector_type(8)));

// Fast exact-enough GELU: v * sigmoid(2u), u = 0.79788456*(v + 0.044715 v^3).
__device__ __forceinline__ float fast_gelu(float v) {
    float v2 = v * v;
    float s  = v * fmaf(0.10294324f, v2, 2.3022079f);  // 2*log2e*0.79788456*(v+0.044715v^3)
    float e  = exp2f(-s);                               // = exp(-2u)
    return v * __builtin_amdgcn_rcpf(1.0f + e);         // v * sigmoid(2u)
}

__device__ __forceinline__ float bfbits2f(unsigned short h) {
    return __uint_as_float(((unsigned)h) << 16);
}

__device__ __forceinline__ short f2bf_bits(float f) {
    __hip_bfloat16 b = __float2bfloat16(f);
    return *reinterpret_cast<short*>(&b);
}

// ---------------- K transpose+cast for BOTH weights (+ meta zero) -----------
// blocks [0,256): W1 (E,256,512)->(E,512,256); blocks [256,512): W2 -> (E,256,512)
__global__ __launch_bounds__(256) void k_transpose_both(
    const float* __restrict__ W1, const float* __restrict__ W2,
    __hip_bfloat16* __restrict__ w1t, __hip_bfloat16* __restrict__ w2t,
    int* __restrict__ meta)
{
    __shared__ float t[64][65];
    if (blockIdx.x == 0 && threadIdx.x < 16) meta[threadIdx.x] = 0;  // counts+cursors
    int bb = blockIdx.x;
    const float* in; __hip_bfloat16* out; int R, CC;
    if (bb < 256) { in = W1; out = w1t; R = 256; CC = 512; }
    else          { in = W2; out = w2t; R = 512; CC = 256; bb -= 256; }
    int tilesC = CC >> 6;
    int per = (R >> 6) * tilesC;
    int e = bb / per, tt = bb % per;
    int r0 = (tt / tilesC) << 6, c0 = (tt % tilesC) << 6;
    const float* ip = in + (size_t)e * R * CC;
    __hip_bfloat16* op = out + (size_t)e * R * CC;
    int lane = threadIdx.x & 63, g = threadIdx.x >> 6;
    for (int i = 0; i < 16; i++) {
        int r = i * 4 + g;
        t[r][lane] = ip[(size_t)(r0 + r) * CC + c0 + lane];
    }
    __syncthreads();
    for (int i = 0; i < 16; i++) {
        int r = i * 4 + g;
        op[(size_t)(c0 + r) * R + r0 + lane] = __float2bfloat16(t[lane][r]);
    }
}

// ---------------- K0: x transpose -> tokens bf16, fp32 router, top2 ---------
__global__ __launch_bounds__(256) void k_router(
    const float* __restrict__ x, const float* __restrict__ Wr, const float* __restrict__ br,
    __hip_bfloat16* __restrict__ tokens, int* __restrict__ pair, float2* __restrict__ wts,
    int* __restrict__ meta /* counts at [0..8) */)
{
    __shared__ float xt[CCH][66];   // pitch 66: float2-aligned rows, 2-way banks
    __shared__ float wr[CCH][NE];
    __shared__ float lg[64][NE];
    __shared__ int lc[NE];
    int tid = threadIdx.x;
    int n0 = blockIdx.x * 64;
    int b = n0 >> 12, p0 = n0 & 4095;
    const float* xb = x + (size_t)b * CCH * HW + p0;
    for (int i = tid; i < CCH * NE; i += 256) ((float*)wr)[i] = Wr[i];
    if (tid < NE) lc[tid] = 0;
    int lane = tid & 63, wv = tid >> 6;
    // float2-vectorized staged read
    {
        int j2 = tid & 31, cg = tid >> 5;          // pos 2*j2, 8 channel groups
        for (int i = 0; i < 32; i++) {
            int c = cg + 8 * i;
            float2 v = *(const float2*)(xb + (size_t)c * HW + 2 * j2);
            *(float2*)&xt[c][2 * j2] = v;
        }
    }
    __syncthreads();
    float a0 = br[2 * wv], a1 = br[2 * wv + 1];
    for (int c = 0; c < CCH; c++) {
        float xv = xt[c][lane];
        a0 = fmaf(xv, wr[c][2 * wv], a0);
        a1 = fmaf(xv, wr[c][2 * wv + 1], a1);
    }
    lg[lane][2 * wv] = a0;
    lg[lane][2 * wv + 1] = a1;
    __syncthreads();
    if (wv == 0) {
        float v0 = -1e30f, v1 = -1e30f; int i0 = 0, i1 = 0;
        for (int e = 0; e < NE; e++) {
            float l = lg[lane][e];
            if (l > v0)      { v1 = v0; i1 = i0; v0 = l; i0 = e; }
            else if (l > v1) { v1 = l; i1 = e; }
        }
        float e1 = expf(v1 - v0);
        float s = 1.0f + e1;
        wts[n0 + lane] = make_float2(1.0f / s, e1 / s);
        pair[n0 + lane] = i0 | (i1 << 8);
        atomicAdd(&lc[i0], 1);
        atomicAdd(&lc[i1], 1);
    }
    __syncthreads();
    if (tid < NE && lc[tid] > 0) atomicAdd(&meta[tid], lc[tid]);
    // ---- vectorized token write: 8 x short8 (16B) stores per thread
    // thread t: token r = t&63, channel blocks c0 = 64*(t>>6) + 8i
    {
        int r = tid & 63, gb = tid >> 6;
        for (int i = 0; i < 8; i++) {
            int c0 = gb * 64 + i * 8;
            s16x8 v;
#pragma unroll
            for (int j = 0; j < 8; j++) v[j] = f2bf_bits(xt[c0 + j][r]);
            *(s16x8*)(tokens + (size_t)(n0 + r) * CCH + c0) = v;
        }
    }
}

// ---------------- K2: scatter tokens into per-expert lists (scan fused) -----
// meta: [0..8) counts, [8..16) cursors, [16..25) offsets, [25..34) tilestart, [34] total
__global__ __launch_bounds__(256) void k_scatter(
    const int* __restrict__ pair, const float2* __restrict__ wts,
    int* __restrict__ meta, int* __restrict__ assign_tok, float* __restrict__ assign_w,
    int2* __restrict__ tok_slots)
{
    __shared__ int lcount[NE];
    __shared__ int lbase[NE];
    __shared__ int soff[NE];
    int tid = threadIdx.x;
    int n = blockIdx.x * 256 + tid;
    if (tid < NE) lcount[tid] = 0;
    __syncthreads();
    int pr = pair[n];
    int e0 = pr & 0xff, e1 = (pr >> 8) & 0xff;
    int p0 = atomicAdd(&lcount[e0], 1);
    int p1 = atomicAdd(&lcount[e1], 1);
    __syncthreads();
    if (tid == 0) {
        int off = 0, toff = 0;
        for (int ee = 0; ee < NE; ee++) {
            soff[ee] = off;
            int c = meta[ee];
            if (blockIdx.x == 0) { meta[16 + ee] = off; meta[25 + ee] = toff; }
            off += c;
            toff += (c + 63) >> 6;
        }
        if (blockIdx.x == 0) { meta[24] = off; meta[33] = toff; meta[34] = toff; }
    }
    if (tid < NE) lbase[tid] = atomicAdd(&meta[8 + tid], lcount[tid]);
    __syncthreads();
    float2 w = wts[n];
    int s0 = soff[e0] + lbase[e0] + p0;
    int s1 = soff[e1] + lbase[e1] + p1;
    assign_tok[s0] = n; assign_w[s0] = w.x;
    assign_tok[s1] = n; assign_w[s1] = w.y;
    tok_slots[n] = make_int2(s0, s1);
}

// ---------------- K3: grouped fused MLP (the hot kernel) --------------------
// R4 base (XCD swizzle, 4-barrier structure) + R5: half-order stagger by
// ((blockIdx.x>>8)&1) so co-resident blocks anti-correlate GELU(VALU) vs
// GEMM(MFMA) phases. Half order is mathematically irrelevant (oacc sums both).
__global__ __launch_bounds__(512, 4) void k_expert(
    const __hip_bfloat16* __restrict__ tokens,
    const __hip_bfloat16* __restrict__ w1t,   // (E, HID, C)  = W1^T per expert
    const __hip_bfloat16* __restrict__ w2t,   // (E, C, HID)  = W2^T per expert
    const float* __restrict__ b1, const float* __restrict__ b2,
    const int* __restrict__ meta,
    const int* __restrict__ assign_tok, const float* __restrict__ assign_w,
    __hip_bfloat16* __restrict__ ybuf)
{
    __shared__ __align__(16) __hip_bfloat16 Af[64 * 256];      // 32 KB
    __shared__ __align__(16) __hip_bfloat16 Hs[64 * PADH];     // 33.3 KB
    __shared__ float wrow[64];
    __shared__ int trow[64];

    int total = meta[34];
    int swz = (int)blockIdx.x;
    // XCD swizzle: grid 2056 = 8 XCDs x 257 contiguous tiles (bijective)
    int bid = (swz & 7) * 257 + (swz >> 3);
    if (bid >= total) return;
    int e = 0;
    while (e < 7 && bid >= meta[25 + e + 1]) e++;
    int tile = bid - meta[25 + e];
    int cnt = meta[e];
    int r0 = tile << 6;
    int abase = meta[16 + e] + r0;
    int nrows = cnt - r0; if (nrows > 64) nrows = 64;

    int tid = threadIdx.x;
    if (tid < 64) {
        if (tid < nrows) { trow[tid] = assign_tok[abase + tid]; wrow[tid] = assign_w[abase + tid]; }
        else             { trow[tid] = 0; wrow[tid] = 0.0f; }
    }
    __syncthreads();

    // ---- stage A tile into LDS (frag-linear; lane-linear writes => no conflicts)
    {
        uint4* dst = (uint4*)Af;
#pragma unroll
        for (int j = 0; j < 4; j++) {
            int row = j * 16 + (tid & 15);
            int chunk = (tid >> 4) & 31;
            dst[j * 512 + tid] = ((const uint4*)(tokens + (size_t)trow[row] * CCH))[chunk];
        }
    }

    int lane = tid & 63, wv = tid >> 6;      // wv in [0,8)
    int quad = lane >> 4, l15 = lane & 15;

    const __hip_bfloat16* w1e = w1t + (size_t)e * HID * CCH;
    const __hip_bfloat16* w2e = w2t + (size_t)e * CCH * HID;
    const float* b1e = b1 + e * HID;
    const float* b2e = b2 + e * CCH;

    const s16x8* apb = (const s16x8*)Af + quad * 16 + l15;   // + mt*512 + kk*64

    auto G1Q = [&](int h, int off) {
        return (const s16x8*)(w1e + (size_t)(h * 256 + wv * 32 + off + l15) * CCH) + quad;
    };
    auto G2Q = [&](int h, int off) {
        return (const s16x8*)(w2e + (size_t)(wv * 32 + off + l15) * HID + h * 256) + quad;
    };

    int hfirst = (swz >> 8) & 1;             // phase stagger across co-resident blocks

    f32x4 oacc[4][2];
#pragma unroll
    for (int i = 0; i < 4; i++)
#pragma unroll
        for (int j = 0; j < 2; j++) oacc[i][j] = (f32x4){0.f, 0.f, 0.f, 0.f};

    // issue first-half GEMM1 B-frags and epilogue biases before the A barrier
    s16x8 bf0 = G1Q(hfirst, 0)[0], bf1 = G1Q(hfirst, 16)[0];
    float ob0 = b2e[wv * 32 + l15];
    float ob1 = b2e[wv * 32 + 16 + l15];

    __syncthreads();   // A tile visible (barrier drain also completes bf0/bf1)

#pragma unroll
    for (int hh = 0; hh < 2; hh++) {
        int h = hh ^ hfirst;
        const s16x8* bq0 = G1Q(h, 0);
        const s16x8* bq1 = G1Q(h, 16);

        f32x4 hacc[4][2];
#pragma unroll
        for (int i = 0; i < 4; i++)
#pragma unroll
            for (int j = 0; j < 2; j++) hacc[i][j] = (f32x4){0.f, 0.f, 0.f, 0.f};

        // ---- GEMM1: hacc[mt][nt] over K=256
#pragma unroll
        for (int kk = 0; kk < 8; kk++) {
            s16x8 bn0, bn1;
            if (kk < 7) { bn0 = bq0[(kk + 1) * 4]; bn1 = bq1[(kk + 1) * 4]; }
            s16x8 af[4];
#pragma unroll
            for (int mt = 0; mt < 4; mt++) af[mt] = apb[mt * 512 + kk * 4 * 16];
            __builtin_amdgcn_s_setprio(1);
#pragma unroll
            for (int mt = 0; mt < 4; mt++) {
                hacc[mt][0] = __builtin_amdgcn_mfma_f32_16x16x32_bf16(af[mt], bf0, hacc[mt][0], 0, 0, 0);
                hacc[mt][1] = __builtin_amdgcn_mfma_f32_16x16x32_bf16(af[mt], bf1, hacc[mt][1], 0, 0, 0);
            }
            __builtin_amdgcn_s_setprio(0);
            bf0 = bn0; bf1 = bn1;
        }

        // issue next-phase operands early (completed under GELU / barrier drain)
        const s16x8* b2q0 = G2Q(h, 0);
        const s16x8* b2q1 = G2Q(h, 16);
        s16x8 cf0 = b2q0[0], cf1 = b2q1[0];
        float biasA = b1e[h * 256 + wv * 32 + l15];
        float biasB = b1e[h * 256 + wv * 32 + 16 + l15];
        if (hh == 0) { int h2 = h ^ 1; bf0 = G1Q(h2, 0)[0]; bf1 = G1Q(h2, 16)[0]; }

        // Barrier needed only on the SECOND iteration (Hs reuse); first
        // iteration's Hs is untouched since block start.
        if (hh == 1) __syncthreads();

        // ---- bias + fast GELU -> Hs (local col cl in [0,256))
#pragma unroll
        for (int nt = 0; nt < 2; nt++) {
            int cl = wv * 32 + nt * 16 + l15;
            float bias = nt ? biasB : biasA;
#pragma unroll
            for (int mt = 0; mt < 4; mt++)
#pragma unroll
                for (int r = 0; r < 4; r++) {
                    int row = mt * 16 + quad * 4 + r;
                    float v = hacc[mt][nt][r] + bias;
                    Hs[row * PADH + cl] = __float2bfloat16(fast_gelu(v));
                }
        }
        __syncthreads();   // Hs complete before GEMM2 reads

        // ---- GEMM2: A = Hs rows (LDS), B = W2^T rows (global/L2), K=256
#pragma unroll
        for (int kk = 0; kk < 8; kk++) {
            s16x8 cn0, cn1;
            if (kk < 7) { cn0 = b2q0[(kk + 1) * 4]; cn1 = b2q1[(kk + 1) * 4]; }
            s16x8 hf[4];
#pragma unroll
            for (int mt = 0; mt < 4; mt++)
                hf[mt] = *(const s16x8*)(Hs + (mt * 16 + l15) * PADH + kk * 32 + quad * 8);
            __builtin_amdgcn_s_setprio(1);
#pragma unroll
            for (int mt = 0; mt < 4; mt++) {
                oacc[mt][0] = __builtin_amdgcn_mfma_f32_16x16x32_bf16(hf[mt], cf0, oacc[mt][0], 0, 0, 0);
                oacc[mt][1] = __builtin_amdgcn_mfma_f32_16x16x32_bf16(hf[mt], cf1, oacc[mt][1], 0, 0, 0);
            }
            __builtin_amdgcn_s_setprio(0);
            cf0 = cn0; cf1 = cn1;
        }
        // no barrier here: the hh==1 pre-GELU barrier protects Hs
    }

    // ---- epilogue: (acc + b2) * route_weight -> ybuf[slot][c] bf16
#pragma unroll
    for (int nt = 0; nt < 2; nt++) {
        int cc = wv * 32 + nt * 16 + l15;
        float bias = nt ? ob1 : ob0;
#pragma unroll
        for (int mt = 0; mt < 4; mt++) {
#pragma unroll
            for (int r = 0; r < 4; r++) {
                int row = mt * 16 + quad * 4 + r;
                if (row < nrows) {
                    float v = (oacc[mt][nt][r] + bias) * wrow[row];
                    ybuf[(size_t)(abase + row) * CCH + cc] = __float2bfloat16(v);
                }
            }
        }
    }
}

// ---------------- K4: combine two expert outputs, transpose back, residual --
// 32-token tiles, 4 blocks/CU. R5: gather-phase mapping r=tid&31 (32 banks
// spread) -> moe LDS writes 2-way (was 8-way) conflicted.
__global__ __launch_bounds__(256) void k_combine(
    const float* __restrict__ x, const __hip_bfloat16* __restrict__ ybuf,
    const int2* __restrict__ tok_slots, const float* __restrict__ scale,
    float* __restrict__ out)
{
    __shared__ float moe[CCH][33];   // [channel][token], 33.8 KB
    __shared__ int2 slots[32];
    int tid = threadIdx.x;
    int n0 = blockIdx.x * 32;
    if (tid < 32) slots[tid] = tok_slots[n0 + tid];
    __syncthreads();
    {
        int r = tid & 31, g0 = tid >> 5;       // 8 channel-groups per iter
#pragma unroll
        for (int it = 0; it < 2; it++) {
            int g = g0 + 8 * it;               // 16 channel groups of 16
            int2 s = slots[r];
            const u16x8* px = (const u16x8*)(ybuf + (size_t)s.x * CCH + 16 * g);
            const u16x8* py = (const u16x8*)(ybuf + (size_t)s.y * CCH + 16 * g);
            u16x8 ax0 = px[0], ax1 = px[1], ay0 = py[0], ay1 = py[1];
#pragma unroll
            for (int k = 0; k < 8; k++) {
                moe[16 * g + k][r]     = bfbits2f(ax0[k]) + bfbits2f(ay0[k]);
                moe[16 * g + 8 + k][r] = bfbits2f(ax1[k]) + bfbits2f(ay1[k]);
            }
        }
    }
    __syncthreads();
    float sc = scale[0];
    int b = n0 >> 12, p0 = n0 & 4095;
    const float* xb = x + (size_t)b * CCH * HW + p0;
    float* ob = out + (size_t)b * CCH * HW + p0;
    int j = tid & 7, cbase = tid >> 3;         // pos 4j, 32 channels per iter
#pragma unroll
    for (int i = 0; i < 8; i++) {
        int c = cbase + 32 * i;
        float4 xv = *(const float4*)(xb + (size_t)c * HW + 4 * j);
        float4 o;
        o.x = xv.x + sc * moe[c][4 * j];
        o.y = xv.y + sc * moe[c][4 * j + 1];
        o.z = xv.z + sc * moe[c][4 * j + 2];
        o.w = xv.w + sc * moe[c][4 * j + 3];
        *(float4*)(ob + (size_t)c * HW + 4 * j) = o;
    }
}

// ---------------- launch ----------------------------------------------------
extern "C" void kernel_launch(void* const* d_in, const int* in_sizes, int n_in,
                              void* d_out, int out_size, void* d_ws, size_t ws_size,
                              hipStream_t stream)
{
    const float* x     = (const float*)d_in[0];
    const float* Wr    = (const float*)d_in[1];
    const float* br    = (const float*)d_in[2];
    const float* W1    = (const float*)d_in[3];
    const float* b1    = (const float*)d_in[4];
    const float* W2    = (const float*)d_in[5];
    const float* b2    = (const float*)d_in[6];
    const float* scale = (const float*)d_in[7];
    float* out = (float*)d_out;

    char* ws = (char*)d_ws;
    __hip_bfloat16* tokens = (__hip_bfloat16*)(ws);                 // 33,554,432 B
    __hip_bfloat16* w1t    = (__hip_bfloat16*)(ws + 33554432);      //  2,097,152 B
    __hip_bfloat16* w2t    = (__hip_bfloat16*)(ws + 35651584);      //  2,097,152 B
    __hip_bfloat16* ybuf   = (__hip_bfloat16*)(ws + 37748736);      // 67,108,864 B
    int*    assign_tok = (int*)   (ws + 104857600);                 //    524,288 B
    float*  assign_w   = (float*) (ws + 105381888);                 //    524,288 B
    int2*   tok_slots  = (int2*)  (ws + 105906176);                 //    524,288 B
    int*    pair       = (int*)   (ws + 106430464);                 //    262,144 B
    float2* wts        = (float2*)(ws + 106692608);                 //    524,288 B
    int*    meta       = (int*)   (ws + 107216896);                 //        256 B

    k_transpose_both<<<512, 256, 0, stream>>>(W1, W2, w1t, w2t, meta);
    k_router<<<1024, 256, 0, stream>>>(x, Wr, br, tokens, pair, wts, meta);
    k_scatter<<<256, 256, 0, stream>>>(pair, wts, meta, assign_tok, assign_w, tok_slots);
    k_expert<<<2056, 512, 0, stream>>>(tokens, w1t, w2t, b1, b2, meta,
                                       assign_tok, assign_w, ybuf);
    k_combine<<<2048, 256, 0, stream>>>(x, ybuf, tok_slots, scale, out);
}

// Round 6
// 340.589 us; speedup vs baseline: 1.0086x; 1.0086x over previous
//
#include <hip/hip_runtime.h>
#include <hip/hip_bf16.h>
#include <math.h>

#define HW   4096
#define CCH  256
#define NE   8
#define HID  512
#define NTOK 65536
#define PADH 260   // Hs row pitch (elems): +4 pad -> conflict-free writes, 4-way reads

typedef short s16x8 __attribute__((ext_vector_type(8)));
typedef float f32x4 __attribute__((ext_vector_type(4)));
typedef unsigned short u16x8 __attribute__((ext_vector_type(8)));
typedef unsigned short u16x4 __attribute__((ext_vector_type(4)));

// Fast exact-enough GELU: v * sigmoid(2u), u = 0.79788456*(v + 0.044715 v^3).
__device__ __forceinline__ float fast_gelu(float v) {
    float v2 = v * v;
    float s  = v * fmaf(0.10294324f, v2, 2.3022079f);  // 2*log2e*0.79788456*(v+0.044715v^3)
    float e  = exp2f(-s);                               // = exp(-2u)
    return v * __builtin_amdgcn_rcpf(1.0f + e);         // v * sigmoid(2u)
}

__device__ __forceinline__ float bfbits2f(unsigned short h) {
    return __uint_as_float(((unsigned)h) << 16);
}

__device__ __forceinline__ short f2bf_bits(float f) {
    __hip_bfloat16 b = __float2bfloat16(f);
    return *reinterpret_cast<short*>(&b);
}

__device__ __forceinline__ unsigned short f2bf_ubits(float f) {
    __hip_bfloat16 b = __float2bfloat16(f);
    return *reinterpret_cast<unsigned short*>(&b);
}

// ---------------- K transpose+cast for BOTH weights (+ meta zero) -----------
// blocks [0,256): W1 (E,256,512)->(E,512,256); blocks [256,512): W2 -> (E,256,512)
__global__ __launch_bounds__(256) void k_transpose_both(
    const float* __restrict__ W1, const float* __restrict__ W2,
    __hip_bfloat16* __restrict__ w1t, __hip_bfloat16* __restrict__ w2t,
    int* __restrict__ meta)
{
    __shared__ float t[64][65];
    if (blockIdx.x == 0 && threadIdx.x < 16) meta[threadIdx.x] = 0;  // counts+cursors
    int bb = blockIdx.x;
    const float* in; __hip_bfloat16* out; int R, CC;
    if (bb < 256) { in = W1; out = w1t; R = 256; CC = 512; }
    else          { in = W2; out = w2t; R = 512; CC = 256; bb -= 256; }
    int tilesC = CC >> 6;
    int per = (R >> 6) * tilesC;
    int e = bb / per, tt = bb % per;
    int r0 = (tt / tilesC) << 6, c0 = (tt % tilesC) << 6;
    const float* ip = in + (size_t)e * R * CC;
    __hip_bfloat16* op = out + (size_t)e * R * CC;
    int lane = threadIdx.x & 63, g = threadIdx.x >> 6;
    for (int i = 0; i < 16; i++) {
        int r = i * 4 + g;
        t[r][lane] = ip[(size_t)(r0 + r) * CC + c0 + lane];
    }
    __syncthreads();
    for (int i = 0; i < 16; i++) {
        int r = i * 4 + g;
        op[(size_t)(c0 + r) * R + r0 + lane] = __float2bfloat16(t[lane][r]);
    }
}

// ---------------- K0: router, 32-token tiles, fused reg-logits --------------
// R6: logits accumulate in REGISTERS during the staging loop (8 fma per
// streamed float, Wr read as 2x float4 from LDS) -> no 512-scalar-LDS-read
// dot-product phase; xt[256][33] = 33.8KB, total ~44KB -> 3 blocks/CU (was 2).
__global__ __launch_bounds__(256) void k_router(
    const float* __restrict__ x, const float* __restrict__ Wr, const float* __restrict__ br,
    __hip_bfloat16* __restrict__ tokens, int* __restrict__ pair, float2* __restrict__ wts,
    int* __restrict__ meta /* counts at [0..8) */)
{
    __shared__ float xt[CCH][33];      // 33.8 KB
    __shared__ float wrp[2304];        // 9.2 KB: Wr staged [c*8+e]; reused as plg [g][j][9]
    __shared__ float lg[32][NE];
    __shared__ int lc[NE];
    int tid = threadIdx.x;
    int n0 = blockIdx.x * 32;
    int b = n0 >> 12, p0 = n0 & 4095;
    const float* xb = x + (size_t)b * CCH * HW + p0;
    for (int i = tid; i < CCH * NE; i += 256) wrp[i] = Wr[i];
    if (tid < NE) lc[tid] = 0;
    __syncthreads();
    int j = tid & 31, cg = tid >> 5;   // token j, channel-group cg (8 groups x 32 ch)
    float pacc[8];
#pragma unroll
    for (int e = 0; e < 8; e++) pacc[e] = 0.f;
    for (int i = 0; i < 32; i++) {
        int c = cg + 8 * i;
        float xv = xb[(size_t)c * HW + j];
        xt[c][j] = xv;
        const float4* wp = (const float4*)(wrp + c * 8);
        float4 wa = wp[0], wb2 = wp[1];
        pacc[0] = fmaf(xv, wa.x, pacc[0]);
        pacc[1] = fmaf(xv, wa.y, pacc[1]);
        pacc[2] = fmaf(xv, wa.z, pacc[2]);
        pacc[3] = fmaf(xv, wa.w, pacc[3]);
        pacc[4] = fmaf(xv, wb2.x, pacc[4]);
        pacc[5] = fmaf(xv, wb2.y, pacc[5]);
        pacc[6] = fmaf(xv, wb2.z, pacc[6]);
        pacc[7] = fmaf(xv, wb2.w, pacc[7]);
    }
    __syncthreads();                    // all wrp (Wr) reads done; safe to reuse
    float* plg = wrp;                   // [8 groups][32 tokens][stride 9]
#pragma unroll
    for (int e = 0; e < 8; e++) plg[(cg * 32 + j) * 9 + e] = pacc[e];
    __syncthreads();
    {
        int jj = tid & 31, e = tid >> 5;
        float s = br[e];
#pragma unroll
        for (int g = 0; g < 8; g++) s += plg[(g * 32 + jj) * 9 + e];
        lg[jj][e] = s;
    }
    __syncthreads();
    if (tid < 32) {
        float v0 = -1e30f, v1 = -1e30f; int i0 = 0, i1 = 0;
        for (int e = 0; e < NE; e++) {
            float l = lg[tid][e];
            if (l > v0)      { v1 = v0; i1 = i0; v0 = l; i0 = e; }
            else if (l > v1) { v1 = l; i1 = e; }
        }
        float e1 = expf(v1 - v0);
        float s = 1.0f + e1;
        wts[n0 + tid] = make_float2(1.0f / s, e1 / s);
        pair[n0 + tid] = i0 | (i1 << 8);
        atomicAdd(&lc[i0], 1);
        atomicAdd(&lc[i1], 1);
    }
    __syncthreads();
    if (tid < NE && lc[tid] > 0) atomicAdd(&meta[tid], lc[tid]);
    // ---- token write: thread (j, cg) writes chunks cg+8i (16B each)
#pragma unroll
    for (int i = 0; i < 4; i++) {
        int c0 = (cg + 8 * i) * 8;
        s16x8 v;
#pragma unroll
        for (int k = 0; k < 8; k++) v[k] = f2bf_bits(xt[c0 + k][j]);
        *(s16x8*)(tokens + (size_t)(n0 + j) * CCH + c0) = v;
    }
}

// ---------------- K2: scatter tokens into per-expert lists (scan fused) -----
// meta: [0..8) counts, [8..16) cursors, [16..25) offsets, [25..34) tilestart, [34] total
__global__ __launch_bounds__(256) void k_scatter(
    const int* __restrict__ pair, const float2* __restrict__ wts,
    int* __restrict__ meta, int* __restrict__ assign_tok, float* __restrict__ assign_w,
    int2* __restrict__ tok_slots)
{
    __shared__ int lcount[NE];
    __shared__ int lbase[NE];
    __shared__ int soff[NE];
    int tid = threadIdx.x;
    int n = blockIdx.x * 256 + tid;
    if (tid < NE) lcount[tid] = 0;
    __syncthreads();
    int pr = pair[n];
    int e0 = pr & 0xff, e1 = (pr >> 8) & 0xff;
    int p0 = atomicAdd(&lcount[e0], 1);
    int p1 = atomicAdd(&lcount[e1], 1);
    __syncthreads();
    if (tid == 0) {
        int off = 0, toff = 0;
        for (int ee = 0; ee < NE; ee++) {
            soff[ee] = off;
            int c = meta[ee];
            if (blockIdx.x == 0) { meta[16 + ee] = off; meta[25 + ee] = toff; }
            off += c;
            toff += (c + 63) >> 6;
        }
        if (blockIdx.x == 0) { meta[24] = off; meta[33] = toff; meta[34] = toff; }
    }
    if (tid < NE) lbase[tid] = atomicAdd(&meta[8 + tid], lcount[tid]);
    __syncthreads();
    float2 w = wts[n];
    int s0 = soff[e0] + lbase[e0] + p0;
    int s1 = soff[e1] + lbase[e1] + p1;
    assign_tok[s0] = n; assign_w[s0] = w.x;
    assign_tok[s1] = n; assign_w[s1] = w.y;
    tok_slots[n] = make_int2(s0, s1);
}

// ---------------- K3: grouped fused MLP (the hot kernel) --------------------
// R4-proven path: XCD swizzle (grid 2056 = 8*257 bijective), 4-barrier
// structure, cross-barrier operand prefetch, fast GELU, setprio on MFMA.
// (R5 stagger removed: null.)
__global__ __launch_bounds__(512, 4) void k_expert(
    const __hip_bfloat16* __restrict__ tokens,
    const __hip_bfloat16* __restrict__ w1t,   // (E, HID, C)  = W1^T per expert
    const __hip_bfloat16* __restrict__ w2t,   // (E, C, HID)  = W2^T per expert
    const float* __restrict__ b1, const float* __restrict__ b2,
    const int* __restrict__ meta,
    const int* __restrict__ assign_tok, const float* __restrict__ assign_w,
    __hip_bfloat16* __restrict__ ybuf)
{
    __shared__ __align__(16) __hip_bfloat16 Af[64 * 256];      // 32 KB
    __shared__ __align__(16) __hip_bfloat16 Hs[64 * PADH];     // 33.3 KB
    __shared__ float wrow[64];
    __shared__ int trow[64];

    int total = meta[34];
    int swz = (int)blockIdx.x;
    int bid = (swz & 7) * 257 + (swz >> 3);
    if (bid >= total) return;
    int e = 0;
    while (e < 7 && bid >= meta[25 + e + 1]) e++;
    int tile = bid - meta[25 + e];
    int cnt = meta[e];
    int r0 = tile << 6;
    int abase = meta[16 + e] + r0;
    int nrows = cnt - r0; if (nrows > 64) nrows = 64;

    int tid = threadIdx.x;
    if (tid < 64) {
        if (tid < nrows) { trow[tid] = assign_tok[abase + tid]; wrow[tid] = assign_w[abase + tid]; }
        else             { trow[tid] = 0; wrow[tid] = 0.0f; }
    }
    __syncthreads();

    // ---- stage A tile into LDS (frag-linear; lane-linear writes => no conflicts)
    {
        uint4* dst = (uint4*)Af;
#pragma unroll
        for (int j = 0; j < 4; j++) {
            int row = j * 16 + (tid & 15);
            int chunk = (tid >> 4) & 31;
            dst[j * 512 + tid] = ((const uint4*)(tokens + (size_t)trow[row] * CCH))[chunk];
        }
    }

    int lane = tid & 63, wv = tid >> 6;      // wv in [0,8)
    int quad = lane >> 4, l15 = lane & 15;

    const __hip_bfloat16* w1e = w1t + (size_t)e * HID * CCH;
    const __hip_bfloat16* w2e = w2t + (size_t)e * CCH * HID;
    const float* b1e = b1 + e * HID;
    const float* b2e = b2 + e * CCH;

    const s16x8* apb = (const s16x8*)Af + quad * 16 + l15;   // + mt*512 + kk*64

    auto G1Q = [&](int h, int off) {
        return (const s16x8*)(w1e + (size_t)(h * 256 + wv * 32 + off + l15) * CCH) + quad;
    };
    auto G2Q = [&](int h, int off) {
        return (const s16x8*)(w2e + (size_t)(wv * 32 + off + l15) * HID + h * 256) + quad;
    };

    f32x4 oacc[4][2];
#pragma unroll
    for (int i = 0; i < 4; i++)
#pragma unroll
        for (int j = 0; j < 2; j++) oacc[i][j] = (f32x4){0.f, 0.f, 0.f, 0.f};

    // issue h=0 GEMM1 first B-frags and epilogue biases before the A barrier
    s16x8 bf0 = G1Q(0, 0)[0], bf1 = G1Q(0, 16)[0];
    float ob0 = b2e[wv * 32 + l15];
    float ob1 = b2e[wv * 32 + 16 + l15];

    __syncthreads();   // A tile visible (barrier drain also completes bf0/bf1)

#pragma unroll
    for (int h = 0; h < 2; h++) {
        const s16x8* bq0 = G1Q(h, 0);
        const s16x8* bq1 = G1Q(h, 16);

        f32x4 hacc[4][2];
#pragma unroll
        for (int i = 0; i < 4; i++)
#pragma unroll
            for (int j = 0; j < 2; j++) hacc[i][j] = (f32x4){0.f, 0.f, 0.f, 0.f};

        // ---- GEMM1: hacc[mt][nt] over K=256
#pragma unroll
        for (int kk = 0; kk < 8; kk++) {
            s16x8 bn0, bn1;
            if (kk < 7) { bn0 = bq0[(kk + 1) * 4]; bn1 = bq1[(kk + 1) * 4]; }
            s16x8 af[4];
#pragma unroll
            for (int mt = 0; mt < 4; mt++) af[mt] = apb[mt * 512 + kk * 4 * 16];
            __builtin_amdgcn_s_setprio(1);
#pragma unroll
            for (int mt = 0; mt < 4; mt++) {
                hacc[mt][0] = __builtin_amdgcn_mfma_f32_16x16x32_bf16(af[mt], bf0, hacc[mt][0], 0, 0, 0);
                hacc[mt][1] = __builtin_amdgcn_mfma_f32_16x16x32_bf16(af[mt], bf1, hacc[mt][1], 0, 0, 0);
            }
            __builtin_amdgcn_s_setprio(0);
            bf0 = bn0; bf1 = bn1;
        }

        // issue next-phase operands early (completed under GELU / barrier drain)
        const s16x8* b2q0 = G2Q(h, 0);
        const s16x8* b2q1 = G2Q(h, 16);
        s16x8 cf0 = b2q0[0], cf1 = b2q1[0];
        float biasA = b1e[h * 256 + wv * 32 + l15];
        float biasB = b1e[h * 256 + wv * 32 + 16 + l15];
        if (h == 0) { bf0 = G1Q(1, 0)[0]; bf1 = G1Q(1, 16)[0]; }

        // Barrier needed only at h=1 (Hs reuse); h=0's Hs untouched since start.
        if (h == 1) __syncthreads();

        // ---- bias + fast GELU -> Hs (local col cl in [0,256))
#pragma unroll
        for (int nt = 0; nt < 2; nt++) {
            int cl = wv * 32 + nt * 16 + l15;
            float bias = nt ? biasB : biasA;
#pragma unroll
            for (int mt = 0; mt < 4; mt++)
#pragma unroll
                for (int r = 0; r < 4; r++) {
                    int row = mt * 16 + quad * 4 + r;
                    float v = hacc[mt][nt][r] + bias;
                    Hs[row * PADH + cl] = __float2bfloat16(fast_gelu(v));
                }
        }
        __syncthreads();   // Hs complete before GEMM2 reads

        // ---- GEMM2: A = Hs rows (LDS), B = W2^T rows (global/L2), K=256
#pragma unroll
        for (int kk = 0; kk < 8; kk++) {
            s16x8 cn0, cn1;
            if (kk < 7) { cn0 = b2q0[(kk + 1) * 4]; cn1 = b2q1[(kk + 1) * 4]; }
            s16x8 hf[4];
#pragma unroll
            for (int mt = 0; mt < 4; mt++)
                hf[mt] = *(const s16x8*)(Hs + (mt * 16 + l15) * PADH + kk * 32 + quad * 8);
            __builtin_amdgcn_s_setprio(1);
#pragma unroll
            for (int mt = 0; mt < 4; mt++) {
                oacc[mt][0] = __builtin_amdgcn_mfma_f32_16x16x32_bf16(hf[mt], cf0, oacc[mt][0], 0, 0, 0);
                oacc[mt][1] = __builtin_amdgcn_mfma_f32_16x16x32_bf16(hf[mt], cf1, oacc[mt][1], 0, 0, 0);
            }
            __builtin_amdgcn_s_setprio(0);
            cf0 = cn0; cf1 = cn1;
        }
        // no barrier at h=0 end: the h=1 pre-GELU barrier protects Hs
    }

    // ---- epilogue: (acc + b2) * route_weight -> ybuf[slot][c] bf16
#pragma unroll
    for (int nt = 0; nt < 2; nt++) {
        int cc = wv * 32 + nt * 16 + l15;
        float bias = nt ? ob1 : ob0;
#pragma unroll
        for (int mt = 0; mt < 4; mt++) {
#pragma unroll
            for (int r = 0; r < 4; r++) {
                int row = mt * 16 + quad * 4 + r;
                if (row < nrows) {
                    float v = (oacc[mt][nt][r] + bias) * wrow[row];
                    ybuf[(size_t)(abase + row) * CCH + cc] = __float2bfloat16(v);
                }
            }
        }
    }
}

// ---------------- K4: combine two expert outputs, transpose back, residual --
// R6: moe LDS in bf16 [256][36] = 18KB -> 8 blocks/CU (thread cap). One extra
// bf16 rounding on (y0+y1): <=4e-4 at the output after scale 0.1.
__global__ __launch_bounds__(256) void k_combine(
    const float* __restrict__ x, const __hip_bfloat16* __restrict__ ybuf,
    const int2* __restrict__ tok_slots, const float* __restrict__ scale,
    float* __restrict__ out)
{
    __shared__ __align__(16) unsigned short moe[CCH][36];   // 18 KB
    __shared__ int2 slots[32];
    int tid = threadIdx.x;
    int n0 = blockIdx.x * 32;
    if (tid < 32) slots[tid] = tok_slots[n0 + tid];
    __syncthreads();
    {
        int r = tid & 31, g0 = tid >> 5;
#pragma unroll
        for (int it = 0; it < 2; it++) {
            int g = g0 + 8 * it;               // 16 channel groups of 16
            int2 s = slots[r];
            const u16x8* px = (const u16x8*)(ybuf + (size_t)s.x * CCH + 16 * g);
            const u16x8* py = (const u16x8*)(ybuf + (size_t)s.y * CCH + 16 * g);
            u16x8 ax0 = px[0], ax1 = px[1], ay0 = py[0], ay1 = py[1];
#pragma unroll
            for (int k = 0; k < 8; k++) {
                moe[16 * g + k][r]     = f2bf_ubits(bfbits2f(ax0[k]) + bfbits2f(ay0[k]));
                moe[16 * g + 8 + k][r] = f2bf_ubits(bfbits2f(ax1[k]) + bfbits2f(ay1[k]));
            }
        }
    }
    __syncthreads();
    float sc = scale[0];
    int b = n0 >> 12, p0 = n0 & 4095;
    const float* xb = x + (size_t)b * CCH * HW + p0;
    float* ob = out + (size_t)b * CCH * HW + p0;
    int j = tid & 7, cbase = tid >> 3;         // pos 4j, 32 channels per iter
#pragma unroll
    for (int i = 0; i < 8; i++) {
        int c = cbase + 32 * i;
        float4 xv = *(const float4*)(xb + (size_t)c * HW + 4 * j);
        u16x4 mv = *(const u16x4*)&moe[c][4 * j];
        float4 o;
        o.x = xv.x + sc * bfbits2f(mv[0]);
        o.y = xv.y + sc * bfbits2f(mv[1]);
        o.z = xv.z + sc * bfbits2f(mv[2]);
        o.w = xv.w + sc * bfbits2f(mv[3]);
        *(float4*)(ob + (size_t)c * HW + 4 * j) = o;
    }
}

// ---------------- launch ----------------------------------------------------
extern "C" void kernel_launch(void* const* d_in, const int* in_sizes, int n_in,
                              void* d_out, int out_size, void* d_ws, size_t ws_size,
                              hipStream_t stream)
{
    const float* x     = (const float*)d_in[0];
    const float* Wr    = (const float*)d_in[1];
    const float* br    = (const float*)d_in[2];
    const float* W1    = (const float*)d_in[3];
    const float* b1    = (const float*)d_in[4];
    const float* W2    = (const float*)d_in[5];
    const float* b2    = (const float*)d_in[6];
    const float* scale = (const float*)d_in[7];
    float* out = (float*)d_out;

    char* ws = (char*)d_ws;
    __hip_bfloat16* tokens = (__hip_bfloat16*)(ws);                 // 33,554,432 B
    __hip_bfloat16* w1t    = (__hip_bfloat16*)(ws + 33554432);      //  2,097,152 B
    __hip_bfloat16* w2t    = (__hip_bfloat16*)(ws + 35651584);      //  2,097,152 B
    __hip_bfloat16* ybuf   = (__hip_bfloat16*)(ws + 37748736);      // 67,108,864 B
    int*    assign_tok = (int*)   (ws + 104857600);                 //    524,288 B
    float*  assign_w   = (float*) (ws + 105381888);                 //    524,288 B
    int2*   tok_slots  = (int2*)  (ws + 105906176);                 //    524,288 B
    int*    pair       = (int*)   (ws + 106430464);                 //    262,144 B
    float2* wts        = (float2*)(ws + 106692608);                 //    524,288 B
    int*    meta       = (int*)   (ws + 107216896);                 //        256 B

    k_transpose_both<<<512, 256, 0, stream>>>(W1, W2, w1t, w2t, meta);
    k_router<<<2048, 256, 0, stream>>>(x, Wr, br, tokens, pair, wts, meta);
    k_scatter<<<256, 256, 0, stream>>>(pair, wts, meta, assign_tok, assign_w, tok_slots);
    k_expert<<<2056, 512, 0, stream>>>(tokens, w1t, w2t, b1, b2, meta,
                                       assign_tok, assign_w, ybuf);
    k_combine<<<2048, 256, 0, stream>>>(x, ybuf, tok_slots, scale, out);
}